// Round 2
// baseline (2556.371 us; speedup 1.0000x reference)
//
#include <hip/hip_runtime.h>
#include <hip/hip_bf16.h>

#define D_MODEL 256
#define D_STATE 64
#define MCON    64
#define TLEN    1024
#define BATCH   4
#define NEG_INF -1e9f

// ---------------------------------------------------------------------------
// Kernel 1: per-token projections. q = l2norm(x@Wq+bq), k = l2norm(x@Wk+bk),
// v = x@Wv+bv.  One block per token; all f32.
// ---------------------------------------------------------------------------
__global__ __launch_bounds__(256) void proj_kernel(
    const float* __restrict__ x,
    const float* __restrict__ Wq, const float* __restrict__ bq,
    const float* __restrict__ Wk, const float* __restrict__ bk,
    const float* __restrict__ Wv, const float* __restrict__ bv,
    float* __restrict__ q_ws, float* __restrict__ k_ws, float* __restrict__ v_ws)
{
    const int token = blockIdx.x;
    const int tid = threadIdx.x;
    __shared__ float sx[D_MODEL];
    sx[tid] = x[token * D_MODEL + tid];
    __syncthreads();

    // v = x @ Wv + bv  (thread tid owns output dim tid)
    float acc = 0.f;
    #pragma unroll 8
    for (int i = 0; i < D_MODEL; ++i)
        acc += sx[i] * Wv[i * D_MODEL + tid];
    acc += bv[tid];
    v_ws[token * D_MODEL + tid] = acc;

    // q (wave 0) and k (wave 1), each l2-normalized across 64 dims
    if (tid < 128) {
        const int j = tid & 63;
        const float* W  = (tid < 64) ? Wq : Wk;
        const float* bb = (tid < 64) ? bq : bk;
        float a = 0.f;
        #pragma unroll 8
        for (int i = 0; i < D_MODEL; ++i)
            a += sx[i] * W[i * D_STATE + j];
        a += bb[j];
        float s2 = a * a;
        #pragma unroll
        for (int off = 1; off < 64; off <<= 1) s2 += __shfl_xor(s2, off, 64);
        float nrm = fmaxf(sqrtf(s2), 1e-12f);
        float o = a / nrm;
        if (tid < 64) q_ws[token * D_STATE + j] = o;
        else          k_ws[token * D_STATE + j] = o;
    }
}

// ---------------------------------------------------------------------------
// Kernel 2: the sequential concept-memory scan. One block per sequence (B=4).
// State in LDS: centroids C[64][65] (pad -> conflict-free), values V[64][256],
// counts[64], n. 4 barriers/step; q/k/v prefetched one step ahead.
// ---------------------------------------------------------------------------
__global__ __launch_bounds__(256) void scan_kernel(
    const float* __restrict__ q_ws, const float* __restrict__ k_ws,
    const float* __restrict__ v_ws, float* __restrict__ y_ws,
    const float* __restrict__ ls_p)
{
    const int b   = blockIdx.x;
    const int tid = threadIdx.x;
    const int wv  = tid >> 6;   // wave id 0..3
    const int g   = tid & 63;   // lane id
    const float scale = fminf(expf(ls_p[0]), 100.f);

    __shared__ __align__(16) float sV[MCON * D_MODEL];   // 64 KB
    __shared__ __align__(16) float sC[MCON * 65];        // 16.6 KB, ld=65 -> conflict-free
    __shared__ __align__(16) float sQ[2][D_STATE];
    __shared__ __align__(16) float sK[2][D_STATE];
    __shared__ __align__(16) float sW[MCON];
    __shared__ __align__(16) float sSims[MCON];
    __shared__ __align__(16) float sCounts[MCON];
    __shared__ __align__(16) float sZpart[256 * 4];      // 4 KB z partials
    __shared__ float sResPart[4];
    __shared__ float sSelSim;
    __shared__ int   sSel;
    __shared__ int   sN;

    // zero-init state (masked rows must be 0.0, not garbage: w~0 * NaN = NaN)
    for (int i = tid; i < MCON * D_MODEL; i += 256) sV[i] = 0.f;
    for (int i = tid; i < MCON * 65;     i += 256) sC[i] = 0.f;
    if (tid < MCON) sCounts[tid] = 0.f;
    if (tid == 0)   sN = 0;

    const float* qg = q_ws + b * TLEN * D_STATE;
    const float* kg = k_ws + b * TLEN * D_STATE;
    const float* vg = v_ws + b * TLEN * D_MODEL;
    float*       yg = y_ws + b * TLEN * D_MODEL;

    // prefetch t = 0
    float qr = 0.f, kr = 0.f;
    if (tid < 64) { qr = qg[tid]; kr = kg[tid]; }
    float vr = vg[tid];

    for (int t = 0; t < TLEN; ++t) {
        // stage this step's q/k (double-buffered), keep v in register
        if (tid < 64) { sQ[t & 1][tid] = qr; sK[t & 1][tid] = kr; }
        const float vt = vr;

        // prefetch t+1 (results not needed until next loop top)
        const int tn = (t + 1 < TLEN) ? t + 1 : t;
        float qn = 0.f, kn = 0.f;
        if (tid < 64) { qn = qg[tn * D_STATE + tid]; kn = kg[tn * D_STATE + tid]; }
        float vn = vg[tn * D_MODEL + tid];

        __syncthreads();                       // B0: prev updates + sQ/sK visible
        const int n_cur = sN;

        // Phase 1: sims[m] = C[m] . q   (4 partial-threads per row)
        {
            const int m = tid >> 2, part = tid & 3;
            const float* crow = &sC[m * 65 + part * 16];
            const float* qq   = &sQ[t & 1][part * 16];
            float p = 0.f;
            #pragma unroll
            for (int j = 0; j < 16; ++j) p += crow[j] * qq[j];
            p += __shfl_xor(p, 1, 64);
            p += __shfl_xor(p, 2, 64);
            if (part == 0) sSims[m] = p;
        }
        __syncthreads();                       // B1

        // Phase 2: softmax + argmax over weights (first-index tiebreak), wave 0
        if (tid < 64) {
            const int m = tid;
            const float sim = sSims[m];
            const float sc  = (m < n_cur) ? sim : NEG_INF;
            const float l   = sc * scale;
            float mx = l;
            #pragma unroll
            for (int off = 1; off < 64; off <<= 1)
                mx = fmaxf(mx, __shfl_xor(mx, off, 64));
            const float e = expf(l - mx);
            float sm = e;
            #pragma unroll
            for (int off = 1; off < 64; off <<= 1) sm += __shfl_xor(sm, off, 64);
            const float w = e / sm;
            sW[m] = w;
            // argmax over the rounded weights (matches jnp.argmax(weights))
            float bvv = w; int bi = m;
            #pragma unroll
            for (int off = 1; off < 64; off <<= 1) {
                const float ov = __shfl_xor(bvv, off, 64);
                const int   oi = __shfl_xor(bi,  off, 64);
                if (ov > bvv || (ov == bvv && oi < bi)) { bvv = ov; bi = oi; }
            }
            if (m == 0) { sSel = bi; sSelSim = sSims[bi]; }
        }
        __syncthreads();                       // B2

        // Phase 3: residual partials + z partials (reads V pre-update)
        const int   sel   = sSel;
        const float cnt   = sCounts[sel];
        const float vselD = sV[sel * D_MODEL + tid];
        {
            const float d = vselD - vt;
            float r = d * d;
            #pragma unroll
            for (int off = 1; off < 64; off <<= 1) r += __shfl_xor(r, off, 64);
            if (g == 0) sResPart[wv] = r;
        }
        {
            float4 zp = make_float4(0.f, 0.f, 0.f, 0.f);
            const int m0 = wv * 16;           // wave wv handles 16 concepts
            #pragma unroll
            for (int mm = 0; mm < 16; ++mm) {
                const int m = m0 + mm;
                const float w = sW[m];
                const float4 vvv = *(const float4*)&sV[m * D_MODEL + 4 * g];
                zp.x += w * vvv.x; zp.y += w * vvv.y;
                zp.z += w * vvv.z; zp.w += w * vvv.w;
            }
            *(float4*)&sZpart[tid * 4] = zp;
        }
        __syncthreads();                       // B3

        // Phase 4: flags, z finalize + y store, state updates
        const float res2     = sResPart[0] + sResPart[1] + sResPart[2] + sResPart[3];
        const float residual = sqrtf(res2 * (1.f / 256.f));
        const float selSim   = sSelSim;
        const bool has       = n_cur > 0;
        const bool refine    = has && (n_cur < MCON) &&
                               (selSim < 0.75f || residual > 1.0f);
        const bool do_add    = (!has || refine) && (n_cur < MCON);
        const bool do_update = has && !refine;

        const float z = sZpart[tid] + sZpart[256 + tid] +
                        sZpart[512 + tid] + sZpart[768 + tid];
        yg[t * D_MODEL + tid] = has ? z : 0.f;   // x.dtype = f32 -> no rounding

        if (do_update) sV[sel   * D_MODEL + tid] = (vselD * cnt + vt) / (cnt + 1.f);
        if (do_add)    sV[n_cur * D_MODEL + tid] = vt;

        if (tid < 64) {
            const float kk = sK[t & 1][tid];
            if (do_update) {
                const float c   = sC[sel * 65 + tid];
                const float tmp = 0.9f * c + 0.1f * kk;
                float s2 = tmp * tmp;
                #pragma unroll
                for (int off = 1; off < 64; off <<= 1) s2 += __shfl_xor(s2, off, 64);
                sC[sel * 65 + tid] = tmp / fmaxf(sqrtf(s2), 1e-12f);
            }
            if (do_add) sC[n_cur * 65 + tid] = kk;
        }
        if (tid == 0) {
            if (do_update) sCounts[sel] = cnt + 1.f;
            if (do_add) { sCounts[n_cur] = 1.f; sN = n_cur + 1; }
        }

        qr = qn; kr = kn; vr = vn;
    }
}

// ---------------------------------------------------------------------------
// Kernel 3: out = y @ Wo + bo
// ---------------------------------------------------------------------------
__global__ __launch_bounds__(256) void out_kernel(
    const float* __restrict__ y_ws,
    const float* __restrict__ Wo, const float* __restrict__ bo,
    float* __restrict__ out)
{
    const int token = blockIdx.x;
    const int tid = threadIdx.x;
    __shared__ float sy[D_MODEL];
    sy[tid] = y_ws[token * D_MODEL + tid];
    __syncthreads();
    float acc = 0.f;
    #pragma unroll 8
    for (int i = 0; i < D_MODEL; ++i)
        acc += sy[i] * Wo[i * D_MODEL + tid];
    acc += bo[tid];
    out[token * D_MODEL + tid] = acc;
}

// ---------------------------------------------------------------------------
extern "C" void kernel_launch(void* const* d_in, const int* in_sizes, int n_in,
                              void* d_out, int out_size, void* d_ws, size_t ws_size,
                              hipStream_t stream)
{
    const float* x  = (const float*)d_in[0];
    const float* Wq = (const float*)d_in[1];
    const float* bq = (const float*)d_in[2];
    const float* Wk = (const float*)d_in[3];
    const float* bk = (const float*)d_in[4];
    const float* Wv = (const float*)d_in[5];
    const float* bv = (const float*)d_in[6];
    const float* Wo = (const float*)d_in[7];
    const float* bo = (const float*)d_in[8];
    const float* ls = (const float*)d_in[9];
    float* out = (float*)d_out;

    const int NTOK = BATCH * TLEN;                 // 4096
    char* ws = (char*)d_ws;
    float* q_ws = (float*)ws;                                       // 1 MB
    float* k_ws = (float*)(ws + (size_t)NTOK * D_STATE * 4);        // 1 MB
    float* v_ws = (float*)(ws + (size_t)NTOK * D_STATE * 8);        // 4 MB
    float* y_ws = (float*)(ws + (size_t)NTOK * D_STATE * 8
                              + (size_t)NTOK * D_MODEL * 4);        // 4 MB

    proj_kernel<<<NTOK, 256, 0, stream>>>(x, Wq, bq, Wk, bk, Wv, bv,
                                          q_ws, k_ws, v_ws);
    scan_kernel<<<BATCH, 256, 0, stream>>>(q_ws, k_ws, v_ws, y_ws, ls);
    out_kernel<<<NTOK, 256, 0, stream>>>(y_ws, Wo, bo, out);
}